// Round 2
// baseline (1288.456 us; speedup 1.0000x reference)
//
#include <hip/hip_runtime.h>
#include <math.h>

#define L_TOK 32768

__device__ __forceinline__ float gelu_exact(float x) {
    return 0.5f * x * (1.0f + erff(x * 0.7071067811865475f));
}
__device__ __forceinline__ float dot4(float4 a, float4 b) {
    return a.x*b.x + a.y*b.y + a.z*b.z + a.w*b.w;
}

// ---------------- prep: transpose conv weights to [tap][cin][cout] ----------------
__global__ void prep_weights(const float* __restrict__ w1, const float* __restrict__ w2,
                             float* __restrict__ w1t, float* __restrict__ w2t) {
    int t = blockIdx.x * 256 + threadIdx.x;
    if (t < 32*96*27) {            // conv1_w [32][96][27] -> w1t[27][96][32]
        int oc = t / 2592, r = t % 2592;
        int c = r / 27, tap = r % 27;
        w1t[(tap*96 + c)*32 + oc] = w1[t];
    }
    if (t < 96*32*27) {            // conv2_w [96][32][27] -> w2t[27][32][96]
        int oc = t / 864, r = t % 864;
        int c = r / 27, tap = r % 27;
        w2t[(tap*32 + c)*96 + oc] = w2[t];
    }
}

// ---------------- bias table: bias[h][n][m] = rpbt[rpi[n][m]][h] ----------------
__global__ void bias_gather(const int* __restrict__ rpi, const float* __restrict__ rpbt,
                            float* __restrict__ bias) {
    int t = blockIdx.x * 256 + threadIdx.x;
    if (t >= 512*512) return;
    int idx = rpi[t];
    #pragma unroll
    for (int h = 0; h < 6; ++h)
        bias[(size_t)h * 262144 + t] = rpbt[idx * 6 + h];
}

// ---------------- LayerNorm1: one wave per row ----------------
__global__ __launch_bounds__(256) void ln1_kernel(const float* __restrict__ x,
        const float* __restrict__ g, const float* __restrict__ b, float* __restrict__ out) {
    int row = blockIdx.x * 4 + (threadIdx.x >> 6);
    int lane = threadIdx.x & 63;
    const float* xr = x + (size_t)row * 96;
    float v0 = xr[lane];
    float v1 = (lane < 32) ? xr[64 + lane] : 0.0f;
    float s = v0 + v1, ss = v0*v0 + v1*v1;
    #pragma unroll
    for (int m = 32; m; m >>= 1) { s += __shfl_xor(s, m); ss += __shfl_xor(ss, m); }
    float mu = s * (1.0f/96.0f);
    float var = ss * (1.0f/96.0f) - mu*mu;
    float rs = rsqrtf(var + 1e-5f);
    float* orow = out + (size_t)row * 96;
    orow[lane] = (v0 - mu) * rs * g[lane] + b[lane];
    if (lane < 32) orow[64+lane] = (v1 - mu) * rs * g[64+lane] + b[64+lane];
}

// ---------------- generic tiled fp32 GEMM: C = act(A[M,K] @ B[N,K]^T + bias) (+res) ----------------
template<int ACT, int RES>
__global__ __launch_bounds__(256) void gemm_kernel(const float* __restrict__ A,
        const float* __restrict__ B, const float* __restrict__ bias,
        const float* __restrict__ res, float* __restrict__ Cout, int K, int N) {
    __shared__ float At[96][132];
    __shared__ float Bt[96][36];
    int m0 = blockIdx.x * 128;
    int n0 = blockIdx.y * 32;
    int tid = threadIdx.x;
    int tx = tid & 7, ty = tid >> 3;
    float acc[4][4] = {};
    for (int kc = 0; kc < K; kc += 96) {
        for (int i = tid; i < 128*24; i += 256) {
            int kq = i % 24, r = i / 24;
            float4 av = *(const float4*)(A + (size_t)(m0 + r)*K + kc + kq*4);
            At[kq*4+0][r] = av.x; At[kq*4+1][r] = av.y;
            At[kq*4+2][r] = av.z; At[kq*4+3][r] = av.w;
        }
        for (int i = tid; i < 32*24; i += 256) {
            int kq = i % 24, j = i / 24;
            float4 bv = *(const float4*)(B + (size_t)(n0 + j)*K + kc + kq*4);
            Bt[kq*4+0][j] = bv.x; Bt[kq*4+1][j] = bv.y;
            Bt[kq*4+2][j] = bv.z; Bt[kq*4+3][j] = bv.w;
        }
        __syncthreads();
        #pragma unroll 8
        for (int k = 0; k < 96; ++k) {
            float4 a4 = *(const float4*)&At[k][ty*4];
            float4 b4 = *(const float4*)&Bt[k][tx*4];
            float ar[4] = {a4.x, a4.y, a4.z, a4.w};
            float br[4] = {b4.x, b4.y, b4.z, b4.w};
            #pragma unroll
            for (int i = 0; i < 4; ++i)
                #pragma unroll
                for (int j = 0; j < 4; ++j)
                    acc[i][j] += ar[i] * br[j];
        }
        __syncthreads();
    }
    #pragma unroll
    for (int i = 0; i < 4; ++i) {
        int row = m0 + ty*4 + i;
        float o[4];
        #pragma unroll
        for (int j = 0; j < 4; ++j) {
            float v = acc[i][j] + bias[n0 + tx*4 + j];
            if (ACT == 1) v = gelu_exact(v);
            if (RES) v += res[(size_t)row * N + n0 + tx*4 + j];
            o[j] = v;
        }
        *(float4*)(Cout + (size_t)row * N + n0 + tx*4) = make_float4(o[0], o[1], o[2], o[3]);
    }
}

// ---------------- conv1 (96 -> 32, 3x3x3, SAME) + exact GELU ----------------
__global__ __launch_bounds__(256) void conv1_kernel(const float* __restrict__ xn,
        const float* __restrict__ w1t, const float* __restrict__ b1, float* __restrict__ c1out) {
    int idx = blockIdx.x * 256 + threadIdx.x;      // 131072 = 32768 voxels x 4 oc-quarters
    int v = idx & (L_TOK - 1);
    int quart = idx >> 15;                          // uniform per block
    int oc0 = quart * 8;
    int d = v >> 12, hh = (v >> 6) & 63, ww = v & 63;
    float acc[8];
    #pragma unroll
    for (int i = 0; i < 8; ++i) acc[i] = b1[oc0 + i];
    #pragma unroll
    for (int kd = -1; kd <= 1; ++kd) {
        int dd = d + kd;
        if ((unsigned)dd >= 8u) continue;
        #pragma unroll
        for (int kh = -1; kh <= 1; ++kh) {
            int h2 = hh + kh;
            if ((unsigned)h2 >= 64u) continue;
            #pragma unroll
            for (int kw = -1; kw <= 1; ++kw) {
                int w2 = ww + kw;
                if ((unsigned)w2 >= 64u) continue;
                int tap = (kd+1)*9 + (kh+1)*3 + (kw+1);
                const float* inp = xn + (size_t)((dd*64 + h2)*64 + w2) * 96;
                const float* wp = w1t + tap*3072 + oc0;
                #pragma unroll 4
                for (int cq = 0; cq < 24; ++cq) {
                    float4 in4 = *(const float4*)(inp + cq*4);
                    float iv[4] = {in4.x, in4.y, in4.z, in4.w};
                    #pragma unroll
                    for (int cc = 0; cc < 4; ++cc) {
                        const float* wr = wp + (cq*4 + cc)*32;
                        float4 w0 = *(const float4*)(wr);
                        float4 w1v = *(const float4*)(wr + 4);
                        float xv = iv[cc];
                        acc[0] += xv*w0.x;  acc[1] += xv*w0.y;
                        acc[2] += xv*w0.z;  acc[3] += xv*w0.w;
                        acc[4] += xv*w1v.x; acc[5] += xv*w1v.y;
                        acc[6] += xv*w1v.z; acc[7] += xv*w1v.w;
                    }
                }
            }
        }
    }
    float* op = c1out + (size_t)v*32 + oc0;
    *(float4*)op     = make_float4(gelu_exact(acc[0]), gelu_exact(acc[1]), gelu_exact(acc[2]), gelu_exact(acc[3]));
    *(float4*)(op+4) = make_float4(gelu_exact(acc[4]), gelu_exact(acc[5]), gelu_exact(acc[6]), gelu_exact(acc[7]));
}

// ---------------- conv2 (32 -> 96, 3x3x3, SAME), no activation ----------------
__global__ __launch_bounds__(256) void conv2_kernel(const float* __restrict__ c1,
        const float* __restrict__ w2t, const float* __restrict__ b2, float* __restrict__ y2) {
    int idx = blockIdx.x * 256 + threadIdx.x;      // 131072
    int v = idx & (L_TOK - 1);
    int quart = idx >> 15;
    int oc0 = quart * 24;
    int d = v >> 12, hh = (v >> 6) & 63, ww = v & 63;
    float acc[24];
    #pragma unroll
    for (int i = 0; i < 24; ++i) acc[i] = b2[oc0 + i];
    #pragma unroll
    for (int kd = -1; kd <= 1; ++kd) {
        int dd = d + kd;
        if ((unsigned)dd >= 8u) continue;
        #pragma unroll
        for (int kh = -1; kh <= 1; ++kh) {
            int h2 = hh + kh;
            if ((unsigned)h2 >= 64u) continue;
            #pragma unroll
            for (int kw = -1; kw <= 1; ++kw) {
                int w2 = ww + kw;
                if ((unsigned)w2 >= 64u) continue;
                int tap = (kd+1)*9 + (kh+1)*3 + (kw+1);
                const float* inp = c1 + (size_t)((dd*64 + h2)*64 + w2) * 32;
                const float* wp = w2t + tap*3072 + oc0;
                #pragma unroll 2
                for (int cq = 0; cq < 8; ++cq) {
                    float4 in4 = *(const float4*)(inp + cq*4);
                    float iv[4] = {in4.x, in4.y, in4.z, in4.w};
                    #pragma unroll
                    for (int cc = 0; cc < 4; ++cc) {
                        const float* wr = wp + (cq*4 + cc)*96;
                        float xv = iv[cc];
                        #pragma unroll
                        for (int jw = 0; jw < 6; ++jw) {
                            float4 wv = *(const float4*)(wr + jw*4);
                            acc[jw*4+0] += xv*wv.x; acc[jw*4+1] += xv*wv.y;
                            acc[jw*4+2] += xv*wv.z; acc[jw*4+3] += xv*wv.w;
                        }
                    }
                }
            }
        }
    }
    float* op = y2 + (size_t)v*96 + oc0;
    #pragma unroll
    for (int jw = 0; jw < 6; ++jw)
        *(float4*)(op + jw*4) = make_float4(acc[jw*4+0], acc[jw*4+1], acc[jw*4+2], acc[jw*4+3]);
}

// ---------------- global average pool (column sums, atomic) ----------------
__global__ void pool_kernel(const float* __restrict__ y2, float* __restrict__ p) {
    int c = threadIdx.x;               // block 128, 96 active
    if (c >= 96) return;
    int r0 = blockIdx.x * 64;
    float s = 0.0f;
    for (int r = 0; r < 64; ++r) s += y2[(size_t)(r0 + r)*96 + c];
    atomicAdd(&p[c], s);
}

// ---------------- channel attention: a = sigmoid(W2 relu(W1 mean + b1) + b2) ----------------
__global__ void ca_kernel(const float* __restrict__ p, const float* __restrict__ w1,
                          const float* __restrict__ b1, const float* __restrict__ w2,
                          const float* __restrict__ b2, float* __restrict__ a) {
    __shared__ float a1[3];
    int t = threadIdx.x;               // block 64
    if (t < 3) {
        float s = b1[t];
        for (int c = 0; c < 96; ++c) s += w1[t*96 + c] * (p[c] * (1.0f/32768.0f));
        a1[t] = fmaxf(s, 0.0f);
    }
    __syncthreads();
    for (int c = t; c < 96; c += 64) {
        float s = b2[c] + w2[c*3+0]*a1[0] + w2[c*3+1]*a1[1] + w2[c*3+2]*a1[2];
        a[c] = 1.0f / (1.0f + __expf(-s));
    }
}

// ---------------- windowed attention: one block per (window, head) ----------------
__global__ __launch_bounds__(256, 2) void attn_kernel(const float* __restrict__ qkv,
        const float* __restrict__ bias, float* __restrict__ oatt) {
    __shared__ float Ksh[512][16];
    __shared__ float Vsh[512][16];     // exactly 64 KiB
    int blk = blockIdx.x;
    int win = blk & 63;
    int h = blk >> 6;
    int hb = win >> 3, wb = win & 7;
    int tid = threadIdx.x;
    for (int n = tid; n < 512; n += 256) {
        int zd = n >> 6, zh = (n >> 3) & 7, zw = n & 7;
        int l = zd*4096 + (hb*8 + zh)*64 + wb*8 + zw;
        const float* kr = qkv + (size_t)l*288 + 96 + h*16;
        #pragma unroll
        for (int dq = 0; dq < 4; ++dq) {
            *(float4*)&Ksh[n][dq*4] = *(const float4*)(kr + dq*4);
            *(float4*)&Vsh[n][dq*4] = *(const float4*)(kr + 96 + dq*4);
        }
    }
    __syncthreads();
    int wave = tid >> 6, lane = tid & 63;
    int q0 = wave*64 + lane;
    int q1 = 256 + q0;
    int zd0 = q0 >> 6, zh0 = (q0 >> 3) & 7, zw0 = q0 & 7;
    int l0 = zd0*4096 + (hb*8 + zh0)*64 + wb*8 + zw0;
    int zd1 = q1 >> 6, zh1 = (q1 >> 3) & 7, zw1 = q1 & 7;
    int l1 = zd1*4096 + (hb*8 + zh1)*64 + wb*8 + zw1;
    float4 qa[4], qb[4];
    const float* q0p = qkv + (size_t)l0*288 + h*16;
    const float* q1p = qkv + (size_t)l1*288 + h*16;
    #pragma unroll
    for (int dq = 0; dq < 4; ++dq) {
        float4 t0 = *(const float4*)(q0p + dq*4);
        t0.x *= 0.25f; t0.y *= 0.25f; t0.z *= 0.25f; t0.w *= 0.25f;
        qa[dq] = t0;
        float4 t1 = *(const float4*)(q1p + dq*4);
        t1.x *= 0.25f; t1.y *= 0.25f; t1.z *= 0.25f; t1.w *= 0.25f;
        qb[dq] = t1;
    }
    const float* brow0 = bias + (size_t)h*262144 + (size_t)q0*512;
    const float* brow1 = bias + (size_t)h*262144 + (size_t)q1*512;
    float m0 = -1e30f, m1 = -1e30f, sum0 = 0.0f, sum1 = 0.0f;
    float4 o0[4], o1[4];
    #pragma unroll
    for (int dq = 0; dq < 4; ++dq) { o0[dq] = make_float4(0,0,0,0); o1[dq] = make_float4(0,0,0,0); }
    for (int kt = 0; kt < 16; ++kt) {
        int kb = kt * 32;
        float s0[32], s1[32];
        #pragma unroll
        for (int jq = 0; jq < 8; ++jq) {
            float4 b0 = *(const float4*)(brow0 + kb + jq*4);
            s0[jq*4+0] = b0.x; s0[jq*4+1] = b0.y; s0[jq*4+2] = b0.z; s0[jq*4+3] = b0.w;
            float4 b1v = *(const float4*)(brow1 + kb + jq*4);
            s1[jq*4+0] = b1v.x; s1[jq*4+1] = b1v.y; s1[jq*4+2] = b1v.z; s1[jq*4+3] = b1v.w;
        }
        #pragma unroll
        for (int j = 0; j < 32; ++j) {
            float a0 = s0[j], a1v = s1[j];
            #pragma unroll
            for (int dq = 0; dq < 4; ++dq) {
                float4 kv = *(const float4*)&Ksh[kb + j][dq*4];
                a0  += dot4(qa[dq], kv);
                a1v += dot4(qb[dq], kv);
            }
            s0[j] = a0; s1[j] = a1v;
        }
        float tm0 = s0[0], tm1 = s1[0];
        #pragma unroll
        for (int j = 1; j < 32; ++j) { tm0 = fmaxf(tm0, s0[j]); tm1 = fmaxf(tm1, s1[j]); }
        float nm0 = fmaxf(m0, tm0), nm1 = fmaxf(m1, tm1);
        float c0 = __expf(m0 - nm0), c1v = __expf(m1 - nm1);
        m0 = nm0; m1 = nm1;
        sum0 *= c0; sum1 *= c1v;
        #pragma unroll
        for (int dq = 0; dq < 4; ++dq) {
            o0[dq].x *= c0;  o0[dq].y *= c0;  o0[dq].z *= c0;  o0[dq].w *= c0;
            o1[dq].x *= c1v; o1[dq].y *= c1v; o1[dq].z *= c1v; o1[dq].w *= c1v;
        }
        #pragma unroll
        for (int j = 0; j < 32; ++j) {
            float p0 = __expf(s0[j] - nm0);
            float p1 = __expf(s1[j] - nm1);
            sum0 += p0; sum1 += p1;
            s0[j] = p0; s1[j] = p1;
        }
        #pragma unroll
        for (int j = 0; j < 32; ++j) {
            float p0 = s0[j], p1 = s1[j];
            #pragma unroll
            for (int dq = 0; dq < 4; ++dq) {
                float4 vv = *(const float4*)&Vsh[kb + j][dq*4];
                o0[dq].x += p0*vv.x; o0[dq].y += p0*vv.y; o0[dq].z += p0*vv.z; o0[dq].w += p0*vv.w;
                o1[dq].x += p1*vv.x; o1[dq].y += p1*vv.y; o1[dq].z += p1*vv.z; o1[dq].w += p1*vv.w;
            }
        }
    }
    float inv0 = 1.0f / sum0, inv1 = 1.0f / sum1;
    float* op0 = oatt + (size_t)l0*96 + h*16;
    float* op1 = oatt + (size_t)l1*96 + h*16;
    #pragma unroll
    for (int dq = 0; dq < 4; ++dq) {
        *(float4*)(op0 + dq*4) = make_float4(o0[dq].x*inv0, o0[dq].y*inv0, o0[dq].z*inv0, o0[dq].w*inv0);
        *(float4*)(op1 + dq*4) = make_float4(o1[dq].x*inv1, o1[dq].y*inv1, o1[dq].z*inv1, o1[dq].w*inv1);
    }
}

// ---------------- residual (x + proj + 0.01*y2*a) + LayerNorm2, fused ----------------
__global__ __launch_bounds__(256) void resid_ln2_kernel(const float* __restrict__ x,
        const float* __restrict__ po, const float* __restrict__ y2, const float* __restrict__ a,
        const float* __restrict__ g, const float* __restrict__ b,
        float* __restrict__ x2, float* __restrict__ xn2) {
    int row = blockIdx.x * 4 + (threadIdx.x >> 6);
    int lane = threadIdx.x & 63;
    size_t base = (size_t)row * 96;
    float v0 = x[base + lane] + po[base + lane] + 0.01f * y2[base + lane] * a[lane];
    float v1 = 0.0f;
    if (lane < 32) {
        int c = 64 + lane;
        v1 = x[base + c] + po[base + c] + 0.01f * y2[base + c] * a[c];
    }
    x2[base + lane] = v0;
    if (lane < 32) x2[base + 64 + lane] = v1;
    float s = v0 + v1, ss = v0*v0 + v1*v1;
    #pragma unroll
    for (int m = 32; m; m >>= 1) { s += __shfl_xor(s, m); ss += __shfl_xor(ss, m); }
    float mu = s * (1.0f/96.0f);
    float var = ss * (1.0f/96.0f) - mu*mu;
    float rs = rsqrtf(var + 1e-5f);
    xn2[base + lane] = (v0 - mu) * rs * g[lane] + b[lane];
    if (lane < 32) xn2[base + 64 + lane] = (v1 - mu) * rs * g[64+lane] + b[64+lane];
}

extern "C" void kernel_launch(void* const* d_in, const int* in_sizes, int n_in,
                              void* d_out, int out_size, void* d_ws, size_t ws_size,
                              hipStream_t stream) {
    const float* x      = (const float*)d_in[0];
    const float* n1g    = (const float*)d_in[1];
    const float* n1b    = (const float*)d_in[2];
    const float* qkv_w  = (const float*)d_in[3];
    const float* qkv_b  = (const float*)d_in[4];
    const float* rpbt   = (const float*)d_in[5];
    const float* proj_w = (const float*)d_in[6];
    const float* proj_b = (const float*)d_in[7];
    const float* c1w    = (const float*)d_in[8];
    const float* c1b    = (const float*)d_in[9];
    const float* c2w    = (const float*)d_in[10];
    const float* c2b    = (const float*)d_in[11];
    const float* ca1w   = (const float*)d_in[12];
    const float* ca1b   = (const float*)d_in[13];
    const float* ca2w   = (const float*)d_in[14];
    const float* ca2b   = (const float*)d_in[15];
    const float* n2g    = (const float*)d_in[16];
    const float* n2b    = (const float*)d_in[17];
    const float* fc1w   = (const float*)d_in[18];
    const float* fc1b   = (const float*)d_in[19];
    const float* fc2w   = (const float*)d_in[20];
    const float* fc2b   = (const float*)d_in[21];
    const int*   rpi    = (const int*)d_in[22];

    // ---- workspace layout with lifetime-based aliasing (floats) ----
    // Region A [0, 3.14M):       xn (LN1 out; dead after qkv+conv1)  -> oat (attn out; dead after proj)
    // Region B [3.14M, 12.58M):  qkvb (dead after attn) -> {po, x2, xn2}
    // Region C [12.58M, 14.15M): bias (dead after attn)        \
    // Region D [14.15M, 15.20M): c1   (dead after conv2)        |-> hbuf [12.58M, 25.17M) for fc1/fc2
    // Region E [15.20M, 18.35M): y2   (dead after resid_ln2)   /
    // tails:   [25.17M, ...):    w1t, w2t, pbuf, abuf
    // peak = 25,165,824 + 166,080 floats ~= 101.3 MB
    float* W    = (float*)d_ws;
    float* xn   = W;                     // 3,145,728
    float* oat  = W;                     // aliases xn
    float* qkvb = W + 3145728;           // 9,437,184
    float* po   = W + 3145728;           // aliases qkvb[0:3.14M)
    float* x2   = W + 6291456;           // aliases qkvb[3.14M:6.29M)
    float* xn2  = W + 9437184;           // aliases qkvb[6.29M:9.44M)
    float* bias = W + 12582912;          // 1,572,864
    float* c1   = W + 14155776;          // 1,048,576
    float* y2   = W + 15204352;          // 3,145,728
    float* hbuf = W + 12582912;          // 12,582,912 (aliases bias+c1+y2+beyond, all dead by fc1)
    float* w1t  = W + 25165824;          // 82,944
    float* w2t  = W + 25248768;          // 82,944
    float* pbuf = W + 25331712;          // 96
    float* abuf = W + 25331808;          // 96

    prep_weights<<<324, 256, 0, stream>>>(c1w, c2w, w1t, w2t);
    bias_gather<<<1024, 256, 0, stream>>>(rpi, rpbt, bias);
    ln1_kernel<<<8192, 256, 0, stream>>>(x, n1g, n1b, xn);
    gemm_kernel<0,0><<<dim3(256, 9), 256, 0, stream>>>(xn, qkv_w, qkv_b, nullptr, qkvb, 96, 288);
    conv1_kernel<<<512, 256, 0, stream>>>(xn, w1t, c1b, c1);
    conv2_kernel<<<512, 256, 0, stream>>>(c1, w2t, c2b, y2);
    hipMemsetAsync(pbuf, 0, 96*sizeof(float), stream);
    pool_kernel<<<512, 128, 0, stream>>>(y2, pbuf);
    ca_kernel<<<1, 64, 0, stream>>>(pbuf, ca1w, ca1b, ca2w, ca2b, abuf);
    attn_kernel<<<384, 256, 0, stream>>>(qkvb, bias, oat);
    gemm_kernel<0,0><<<dim3(256, 3), 256, 0, stream>>>(oat, proj_w, proj_b, nullptr, po, 96, 96);
    resid_ln2_kernel<<<8192, 256, 0, stream>>>(x, po, y2, abuf, n2g, n2b, x2, xn2);
    gemm_kernel<1,0><<<dim3(256, 12), 256, 0, stream>>>(xn2, fc1w, fc1b, nullptr, hbuf, 96, 384);
    gemm_kernel<0,1><<<dim3(256, 3), 256, 0, stream>>>(hbuf, fc2w, fc2b, x2, (float*)d_out, 384, 96);
}

// Round 5
// 1124.055 us; speedup vs baseline: 1.1463x; 1.1463x over previous
//
#include <hip/hip_runtime.h>
#include <math.h>

#define L_TOK 32768

__device__ __forceinline__ float gelu_exact(float x) {
    return 0.5f * x * (1.0f + erff(x * 0.7071067811865475f));
}
__device__ __forceinline__ float dot4(float4 a, float4 b) {
    return a.x*b.x + a.y*b.y + a.z*b.z + a.w*b.w;
}

// ---------------- prep: transpose conv weights to [tap][cin][cout] ----------------
__global__ void prep_weights(const float* __restrict__ w1, const float* __restrict__ w2,
                             float* __restrict__ w1t, float* __restrict__ w2t) {
    int t = blockIdx.x * 256 + threadIdx.x;
    if (t < 32*96*27) {            // conv1_w [32][96][27] -> w1t[27][96][32]
        int oc = t / 2592, r = t % 2592;
        int c = r / 27, tap = r % 27;
        w1t[(tap*96 + c)*32 + oc] = w1[t];
    }
    if (t < 96*32*27) {            // conv2_w [96][32][27] -> w2t[27][32][96]
        int oc = t / 864, r = t % 864;
        int c = r / 27, tap = r % 27;
        w2t[(tap*32 + c)*96 + oc] = w2[t];
    }
}

// ---------------- bias table: bias[h][n][m] = rpbt[rpi[n][m]][h] ----------------
__global__ void bias_gather(const int* __restrict__ rpi, const float* __restrict__ rpbt,
                            float* __restrict__ bias) {
    int t = blockIdx.x * 256 + threadIdx.x;
    if (t >= 512*512) return;
    int idx = rpi[t];
    #pragma unroll
    for (int h = 0; h < 6; ++h)
        bias[(size_t)h * 262144 + t] = rpbt[idx * 6 + h];
}

// ---------------- LayerNorm1: one wave per row ----------------
__global__ __launch_bounds__(256) void ln1_kernel(const float* __restrict__ x,
        const float* __restrict__ g, const float* __restrict__ b, float* __restrict__ out) {
    int row = blockIdx.x * 4 + (threadIdx.x >> 6);
    int lane = threadIdx.x & 63;
    const float* xr = x + (size_t)row * 96;
    float v0 = xr[lane];
    float v1 = (lane < 32) ? xr[64 + lane] : 0.0f;
    float s = v0 + v1, ss = v0*v0 + v1*v1;
    #pragma unroll
    for (int m = 32; m; m >>= 1) { s += __shfl_xor(s, m); ss += __shfl_xor(ss, m); }
    float mu = s * (1.0f/96.0f);
    float var = ss * (1.0f/96.0f) - mu*mu;
    float rs = rsqrtf(var + 1e-5f);
    float* orow = out + (size_t)row * 96;
    orow[lane] = (v0 - mu) * rs * g[lane] + b[lane];
    if (lane < 32) orow[64+lane] = (v1 - mu) * rs * g[64+lane] + b[64+lane];
}

// ---------------- generic tiled fp32 GEMM: C = act(A[M,K] @ B[N,K]^T + bias) (+res) ----------------
template<int ACT, int RES>
__global__ __launch_bounds__(256) void gemm_kernel(const float* __restrict__ A,
        const float* __restrict__ B, const float* __restrict__ bias,
        const float* __restrict__ res, float* __restrict__ Cout, int K, int N) {
    __shared__ float At[96][132];
    __shared__ float Bt[96][36];
    int m0 = blockIdx.x * 128;
    int n0 = blockIdx.y * 32;
    int tid = threadIdx.x;
    int tx = tid & 7, ty = tid >> 3;
    float acc[4][4] = {};
    for (int kc = 0; kc < K; kc += 96) {
        for (int i = tid; i < 128*24; i += 256) {
            int kq = i % 24, r = i / 24;
            float4 av = *(const float4*)(A + (size_t)(m0 + r)*K + kc + kq*4);
            At[kq*4+0][r] = av.x; At[kq*4+1][r] = av.y;
            At[kq*4+2][r] = av.z; At[kq*4+3][r] = av.w;
        }
        for (int i = tid; i < 32*24; i += 256) {
            int kq = i % 24, j = i / 24;
            float4 bv = *(const float4*)(B + (size_t)(n0 + j)*K + kc + kq*4);
            Bt[kq*4+0][j] = bv.x; Bt[kq*4+1][j] = bv.y;
            Bt[kq*4+2][j] = bv.z; Bt[kq*4+3][j] = bv.w;
        }
        __syncthreads();
        #pragma unroll 8
        for (int k = 0; k < 96; ++k) {
            float4 a4 = *(const float4*)&At[k][ty*4];
            float4 b4 = *(const float4*)&Bt[k][tx*4];
            float ar[4] = {a4.x, a4.y, a4.z, a4.w};
            float br[4] = {b4.x, b4.y, b4.z, b4.w};
            #pragma unroll
            for (int i = 0; i < 4; ++i)
                #pragma unroll
                for (int j = 0; j < 4; ++j)
                    acc[i][j] += ar[i] * br[j];
        }
        __syncthreads();
    }
    #pragma unroll
    for (int i = 0; i < 4; ++i) {
        int row = m0 + ty*4 + i;
        float o[4];
        #pragma unroll
        for (int j = 0; j < 4; ++j) {
            float v = acc[i][j] + bias[n0 + tx*4 + j];
            if (ACT == 1) v = gelu_exact(v);
            if (RES) v += res[(size_t)row * N + n0 + tx*4 + j];
            o[j] = v;
        }
        *(float4*)(Cout + (size_t)row * N + n0 + tx*4) = make_float4(o[0], o[1], o[2], o[3]);
    }
}

// ---------------- conv1 (96 -> 32, 3x3x3, SAME) + GELU — LDS row-tiled ----------------
// block = one (d,h) output row (64 voxels); wave g computes oc [g*8, g*8+8)
__global__ __launch_bounds__(256) void conv1_kernel(const float* __restrict__ xn,
        const float* __restrict__ w1t, const float* __restrict__ b1, float* __restrict__ c1out) {
    __shared__ float4 Xs[24][66];      // [cin/4][w+halo], 25.3 KB
    int blk = blockIdx.x;              // 512 = 8 d * 64 h
    int d = blk >> 6, hh = blk & 63;
    int tid = threadIdx.x;
    int w = tid & 63, g = tid >> 6;
    int oc0 = g * 8;
    float acc[8];
    #pragma unroll
    for (int i = 0; i < 8; ++i) acc[i] = b1[oc0 + i];
    for (int kd = -1; kd <= 1; ++kd) {
        int dd = d + kd;
        if ((unsigned)dd >= 8u) continue;
        for (int kh = -1; kh <= 1; ++kh) {
            int h2 = hh + kh;
            if ((unsigned)h2 >= 64u) continue;
            __syncthreads();
            const float* src = xn + (size_t)((dd*64 + h2)*64) * 96;
            for (int i = tid; i < 1536; i += 256) {      // 64 vox x 24 float4
                int v = i / 24, c4 = i % 24;
                Xs[c4][v + 1] = *(const float4*)(src + v*96 + c4*4);
            }
            if (tid < 48) Xs[tid % 24][(tid < 24) ? 0 : 65] = make_float4(0,0,0,0);
            __syncthreads();
            int tapbase = (kd+1)*9 + (kh+1)*3;
            #pragma unroll
            for (int kw = 0; kw < 3; ++kw) {
                const float* wp = w1t + (tapbase + kw)*3072 + oc0;   // [cin][32]
                #pragma unroll 4
                for (int c4 = 0; c4 < 24; ++c4) {
                    float4 xv = Xs[c4][w + kw];
                    float xa[4] = {xv.x, xv.y, xv.z, xv.w};
                    #pragma unroll
                    for (int cc = 0; cc < 4; ++cc) {
                        const float* wr = wp + (c4*4 + cc)*32;
                        float4 w0 = *(const float4*)(wr);
                        float4 w1v = *(const float4*)(wr + 4);
                        float xvv = xa[cc];
                        acc[0] += xvv*w0.x;  acc[1] += xvv*w0.y;
                        acc[2] += xvv*w0.z;  acc[3] += xvv*w0.w;
                        acc[4] += xvv*w1v.x; acc[5] += xvv*w1v.y;
                        acc[6] += xvv*w1v.z; acc[7] += xvv*w1v.w;
                    }
                }
            }
        }
    }
    int v = (d*64 + hh)*64 + w;
    float* op = c1out + (size_t)v*32 + oc0;
    *(float4*)op     = make_float4(gelu_exact(acc[0]), gelu_exact(acc[1]), gelu_exact(acc[2]), gelu_exact(acc[3]));
    *(float4*)(op+4) = make_float4(gelu_exact(acc[4]), gelu_exact(acc[5]), gelu_exact(acc[6]), gelu_exact(acc[7]));
}

// ---------------- conv2 (32 -> 96, 3x3x3, SAME) — LDS row-tiled ----------------
// block = one (d,h) output row; wave g computes oc [g*24, g*24+24)
__global__ __launch_bounds__(256) void conv2_kernel(const float* __restrict__ c1,
        const float* __restrict__ w2t, const float* __restrict__ b2, float* __restrict__ y2) {
    __shared__ float4 Xs[8][66];       // [cin/4][w+halo], 8.4 KB
    int blk = blockIdx.x;
    int d = blk >> 6, hh = blk & 63;
    int tid = threadIdx.x;
    int w = tid & 63, g = tid >> 6;
    int oc0 = g * 24;
    float acc[24];
    #pragma unroll
    for (int i = 0; i < 24; ++i) acc[i] = b2[oc0 + i];
    for (int kd = -1; kd <= 1; ++kd) {
        int dd = d + kd;
        if ((unsigned)dd >= 8u) continue;
        for (int kh = -1; kh <= 1; ++kh) {
            int h2 = hh + kh;
            if ((unsigned)h2 >= 64u) continue;
            __syncthreads();
            const float* src = c1 + (size_t)((dd*64 + h2)*64) * 32;
            for (int i = tid; i < 512; i += 256) {       // 64 vox x 8 float4  (FIXED: was if(i<512))
                int v = i / 8, c4 = i % 8;
                Xs[c4][v + 1] = *(const float4*)(src + v*32 + c4*4);
            }
            if (tid < 16) Xs[tid % 8][(tid < 8) ? 0 : 65] = make_float4(0,0,0,0);
            __syncthreads();
            int tapbase = (kd+1)*9 + (kh+1)*3;
            #pragma unroll
            for (int kw = 0; kw < 3; ++kw) {
                const float* wp = w2t + (tapbase + kw)*3072 + oc0;   // [cin][96]
                #pragma unroll 2
                for (int c4 = 0; c4 < 8; ++c4) {
                    float4 xv = Xs[c4][w + kw];
                    float xa[4] = {xv.x, xv.y, xv.z, xv.w};
                    #pragma unroll
                    for (int cc = 0; cc < 4; ++cc) {
                        const float* wr = wp + (c4*4 + cc)*96;
                        float xvv = xa[cc];
                        #pragma unroll
                        for (int jw = 0; jw < 6; ++jw) {
                            float4 wv = *(const float4*)(wr + jw*4);
                            acc[jw*4+0] += xvv*wv.x; acc[jw*4+1] += xvv*wv.y;
                            acc[jw*4+2] += xvv*wv.z; acc[jw*4+3] += xvv*wv.w;
                        }
                    }
                }
            }
        }
    }
    int v = (d*64 + hh)*64 + w;
    float* op = y2 + (size_t)v*96 + oc0;
    #pragma unroll
    for (int jw = 0; jw < 6; ++jw)
        *(float4*)(op + jw*4) = make_float4(acc[jw*4+0], acc[jw*4+1], acc[jw*4+2], acc[jw*4+3]);
}

// ---------------- global average pool (column sums, atomic) ----------------
__global__ void pool_kernel(const float* __restrict__ y2, float* __restrict__ p) {
    int c = threadIdx.x;               // block 128, 96 active
    if (c >= 96) return;
    int r0 = blockIdx.x * 64;
    float s = 0.0f;
    for (int r = 0; r < 64; ++r) s += y2[(size_t)(r0 + r)*96 + c];
    atomicAdd(&p[c], s);
}

// ---------------- channel attention: a = sigmoid(W2 relu(W1 mean + b1) + b2) ----------------
__global__ void ca_kernel(const float* __restrict__ p, const float* __restrict__ w1,
                          const float* __restrict__ b1, const float* __restrict__ w2,
                          const float* __restrict__ b2, float* __restrict__ a) {
    __shared__ float a1[3];
    int t = threadIdx.x;               // block 64
    if (t < 3) {
        float s = b1[t];
        for (int c = 0; c < 96; ++c) s += w1[t*96 + c] * (p[c] * (1.0f/32768.0f));
        a1[t] = fmaxf(s, 0.0f);
    }
    __syncthreads();
    for (int c = t; c < 96; c += 64) {
        float s = b2[c] + w2[c*3+0]*a1[0] + w2[c*3+1]*a1[1] + w2[c*3+2]*a1[2];
        a[c] = 1.0f / (1.0f + __expf(-s));
    }
}

// ---------------- windowed attention: one block per (window, head) ----------------
__global__ __launch_bounds__(256, 2) void attn_kernel(const float* __restrict__ qkv,
        const float* __restrict__ bias, float* __restrict__ oatt) {
    __shared__ float Ksh[512][16];
    __shared__ float Vsh[512][16];     // exactly 64 KiB
    int blk = blockIdx.x;
    int win = blk & 63;
    int h = blk >> 6;
    int hb = win >> 3, wb = win & 7;
    int tid = threadIdx.x;
    for (int n = tid; n < 512; n += 256) {
        int zd = n >> 6, zh = (n >> 3) & 7, zw = n & 7;
        int l = zd*4096 + (hb*8 + zh)*64 + wb*8 + zw;
        const float* kr = qkv + (size_t)l*288 + 96 + h*16;
        #pragma unroll
        for (int dq = 0; dq < 4; ++dq) {
            *(float4*)&Ksh[n][dq*4] = *(const float4*)(kr + dq*4);
            *(float4*)&Vsh[n][dq*4] = *(const float4*)(kr + 96 + dq*4);
        }
    }
    __syncthreads();
    int wave = tid >> 6, lane = tid & 63;
    int q0 = wave*64 + lane;
    int q1 = 256 + q0;
    int zd0 = q0 >> 6, zh0 = (q0 >> 3) & 7, zw0 = q0 & 7;
    int l0 = zd0*4096 + (hb*8 + zh0)*64 + wb*8 + zw0;
    int zd1 = q1 >> 6, zh1 = (q1 >> 3) & 7, zw1 = q1 & 7;
    int l1 = zd1*4096 + (hb*8 + zh1)*64 + wb*8 + zw1;
    float4 qa[4], qb[4];
    const float* q0p = qkv + (size_t)l0*288 + h*16;
    const float* q1p = qkv + (size_t)l1*288 + h*16;
    #pragma unroll
    for (int dq = 0; dq < 4; ++dq) {
        float4 t0 = *(const float4*)(q0p + dq*4);
        t0.x *= 0.25f; t0.y *= 0.25f; t0.z *= 0.25f; t0.w *= 0.25f;
        qa[dq] = t0;
        float4 t1 = *(const float4*)(q1p + dq*4);
        t1.x *= 0.25f; t1.y *= 0.25f; t1.z *= 0.25f; t1.w *= 0.25f;
        qb[dq] = t1;
    }
    const float* brow0 = bias + (size_t)h*262144 + (size_t)q0*512;
    const float* brow1 = bias + (size_t)h*262144 + (size_t)q1*512;
    float m0 = -1e30f, m1 = -1e30f, sum0 = 0.0f, sum1 = 0.0f;
    float4 o0[4], o1[4];
    #pragma unroll
    for (int dq = 0; dq < 4; ++dq) { o0[dq] = make_float4(0,0,0,0); o1[dq] = make_float4(0,0,0,0); }
    for (int kt = 0; kt < 16; ++kt) {
        int kb = kt * 32;
        float s0[32], s1[32];
        #pragma unroll
        for (int jq = 0; jq < 8; ++jq) {
            float4 b0 = *(const float4*)(brow0 + kb + jq*4);
            s0[jq*4+0] = b0.x; s0[jq*4+1] = b0.y; s0[jq*4+2] = b0.z; s0[jq*4+3] = b0.w;
            float4 b1v = *(const float4*)(brow1 + kb + jq*4);
            s1[jq*4+0] = b1v.x; s1[jq*4+1] = b1v.y; s1[jq*4+2] = b1v.z; s1[jq*4+3] = b1v.w;
        }
        #pragma unroll
        for (int j = 0; j < 32; ++j) {
            float a0 = s0[j], a1v = s1[j];
            #pragma unroll
            for (int dq = 0; dq < 4; ++dq) {
                float4 kv = *(const float4*)&Ksh[kb + j][dq*4];
                a0  += dot4(qa[dq], kv);
                a1v += dot4(qb[dq], kv);
            }
            s0[j] = a0; s1[j] = a1v;
        }
        float tm0 = s0[0], tm1 = s1[0];
        #pragma unroll
        for (int j = 1; j < 32; ++j) { tm0 = fmaxf(tm0, s0[j]); tm1 = fmaxf(tm1, s1[j]); }
        float nm0 = fmaxf(m0, tm0), nm1 = fmaxf(m1, tm1);
        float c0 = __expf(m0 - nm0), c1v = __expf(m1 - nm1);
        m0 = nm0; m1 = nm1;
        sum0 *= c0; sum1 *= c1v;
        #pragma unroll
        for (int dq = 0; dq < 4; ++dq) {
            o0[dq].x *= c0;  o0[dq].y *= c0;  o0[dq].z *= c0;  o0[dq].w *= c0;
            o1[dq].x *= c1v; o1[dq].y *= c1v; o1[dq].z *= c1v; o1[dq].w *= c1v;
        }
        #pragma unroll
        for (int j = 0; j < 32; ++j) {
            float p0 = __expf(s0[j] - nm0);
            float p1 = __expf(s1[j] - nm1);
            sum0 += p0; sum1 += p1;
            s0[j] = p0; s1[j] = p1;
        }
        #pragma unroll
        for (int j = 0; j < 32; ++j) {
            float p0 = s0[j], p1 = s1[j];
            #pragma unroll
            for (int dq = 0; dq < 4; ++dq) {
                float4 vv = *(const float4*)&Vsh[kb + j][dq*4];
                o0[dq].x += p0*vv.x; o0[dq].y += p0*vv.y; o0[dq].z += p0*vv.z; o0[dq].w += p0*vv.w;
                o1[dq].x += p1*vv.x; o1[dq].y += p1*vv.y; o1[dq].z += p1*vv.z; o1[dq].w += p1*vv.w;
            }
        }
    }
    float inv0 = 1.0f / sum0, inv1 = 1.0f / sum1;
    float* op0 = oatt + (size_t)l0*96 + h*16;
    float* op1 = oatt + (size_t)l1*96 + h*16;
    #pragma unroll
    for (int dq = 0; dq < 4; ++dq) {
        *(float4*)(op0 + dq*4) = make_float4(o0[dq].x*inv0, o0[dq].y*inv0, o0[dq].z*inv0, o0[dq].w*inv0);
        *(float4*)(op1 + dq*4) = make_float4(o1[dq].x*inv1, o1[dq].y*inv1, o1[dq].z*inv1, o1[dq].w*inv1);
    }
}

// ---------------- residual (x + proj + 0.01*y2*a) + LayerNorm2, fused ----------------
__global__ __launch_bounds__(256) void resid_ln2_kernel(const float* __restrict__ x,
        const float* __restrict__ po, const float* __restrict__ y2, const float* __restrict__ a,
        const float* __restrict__ g, const float* __restrict__ b,
        float* __restrict__ x2, float* __restrict__ xn2) {
    int row = blockIdx.x * 4 + (threadIdx.x >> 6);
    int lane = threadIdx.x & 63;
    size_t base = (size_t)row * 96;
    float v0 = x[base + lane] + po[base + lane] + 0.01f * y2[base + lane] * a[lane];
    float v1 = 0.0f;
    if (lane < 32) {
        int c = 64 + lane;
        v1 = x[base + c] + po[base + c] + 0.01f * y2[base + c] * a[c];
    }
    x2[base + lane] = v0;
    if (lane < 32) x2[base + 64 + lane] = v1;
    float s = v0 + v1, ss = v0*v0 + v1*v1;
    #pragma unroll
    for (int m = 32; m; m >>= 1) { s += __shfl_xor(s, m); ss += __shfl_xor(ss, m); }
    float mu = s * (1.0f/96.0f);
    float var = ss * (1.0f/96.0f) - mu*mu;
    float rs = rsqrtf(var + 1e-5f);
    xn2[base + lane] = (v0 - mu) * rs * g[lane] + b[lane];
    if (lane < 32) xn2[base + 64 + lane] = (v1 - mu) * rs * g[64+lane] + b[64+lane];
}

extern "C" void kernel_launch(void* const* d_in, const int* in_sizes, int n_in,
                              void* d_out, int out_size, void* d_ws, size_t ws_size,
                              hipStream_t stream) {
    const float* x      = (const float*)d_in[0];
    const float* n1g    = (const float*)d_in[1];
    const float* n1b    = (const float*)d_in[2];
    const float* qkv_w  = (const float*)d_in[3];
    const float* qkv_b  = (const float*)d_in[4];
    const float* rpbt   = (const float*)d_in[5];
    const float* proj_w = (const float*)d_in[6];
    const float* proj_b = (const float*)d_in[7];
    const float* c1w    = (const float*)d_in[8];
    const float* c1b    = (const float*)d_in[9];
    const float* c2w    = (const float*)d_in[10];
    const float* c2b    = (const float*)d_in[11];
    const float* ca1w   = (const float*)d_in[12];
    const float* ca1b   = (const float*)d_in[13];
    const float* ca2w   = (const float*)d_in[14];
    const float* ca2b   = (const float*)d_in[15];
    const float* n2g    = (const float*)d_in[16];
    const float* n2b    = (const float*)d_in[17];
    const float* fc1w   = (const float*)d_in[18];
    const float* fc1b   = (const float*)d_in[19];
    const float* fc2w   = (const float*)d_in[20];
    const float* fc2b   = (const float*)d_in[21];
    const int*   rpi    = (const int*)d_in[22];

    // ---- workspace layout with lifetime-based aliasing (floats) ----
    float* W    = (float*)d_ws;
    float* xn   = W;                     // 3,145,728
    float* oat  = W;                     // aliases xn
    float* qkvb = W + 3145728;           // 9,437,184
    float* po   = W + 3145728;           // aliases qkvb[0:3.14M)
    float* x2   = W + 6291456;           // aliases qkvb[3.14M:6.29M)
    float* xn2  = W + 9437184;           // aliases qkvb[6.29M:9.44M)
    float* bias = W + 12582912;          // 1,572,864
    float* c1   = W + 14155776;          // 1,048,576
    float* y2   = W + 15204352;          // 3,145,728
    float* hbuf = W + 12582912;          // 12,582,912 (aliases bias+c1+y2, dead by fc1)
    float* w1t  = W + 25165824;          // 82,944
    float* w2t  = W + 25248768;          // 82,944
    float* pbuf = W + 25331712;          // 96
    float* abuf = W + 25331808;          // 96

    prep_weights<<<324, 256, 0, stream>>>(c1w, c2w, w1t, w2t);
    bias_gather<<<1024, 256, 0, stream>>>(rpi, rpbt, bias);
    ln1_kernel<<<8192, 256, 0, stream>>>(x, n1g, n1b, xn);
    gemm_kernel<0,0><<<dim3(256, 9), 256, 0, stream>>>(xn, qkv_w, qkv_b, nullptr, qkvb, 96, 288);
    conv1_kernel<<<512, 256, 0, stream>>>(xn, w1t, c1b, c1);
    conv2_kernel<<<512, 256, 0, stream>>>(c1, w2t, c2b, y2);
    hipMemsetAsync(pbuf, 0, 96*sizeof(float), stream);
    pool_kernel<<<512, 128, 0, stream>>>(y2, pbuf);
    ca_kernel<<<1, 64, 0, stream>>>(pbuf, ca1w, ca1b, ca2w, ca2b, abuf);
    attn_kernel<<<384, 256, 0, stream>>>(qkvb, bias, oat);
    gemm_kernel<0,0><<<dim3(256, 3), 256, 0, stream>>>(oat, proj_w, proj_b, nullptr, po, 96, 96);
    resid_ln2_kernel<<<8192, 256, 0, stream>>>(x, po, y2, abuf, n2g, n2b, x2, xn2);
    gemm_kernel<1,0><<<dim3(256, 12), 256, 0, stream>>>(xn2, fc1w, fc1b, nullptr, hbuf, 96, 384);
    gemm_kernel<0,1><<<dim3(256, 3), 256, 0, stream>>>(hbuf, fc2w, fc2b, x2, (float*)d_out, 384, 96);
}

// Round 7
// 569.785 us; speedup vs baseline: 2.2613x; 1.9728x over previous
//
#include <hip/hip_runtime.h>
#include <math.h>

#define L_TOK 32768

typedef __attribute__((ext_vector_type(8))) short bf16x8;
typedef __attribute__((ext_vector_type(4))) float f32x4;

__device__ __forceinline__ float gelu_exact(float x) {
    return 0.5f * x * (1.0f + erff(x * 0.7071067811865475f));
}
__device__ __forceinline__ float dot4(float4 a, float4 b) {
    return a.x*b.x + a.y*b.y + a.z*b.z + a.w*b.w;
}
__device__ __forceinline__ ushort f2bf(float f) {   // RNE fp32->bf16
    unsigned u = __float_as_uint(f);
    u += 0x7fff + ((u >> 16) & 1);
    return (ushort)(u >> 16);
}

// ---------------- prep: pack conv weights into MFMA fragment-ready bf16 buffers ----
// conv1: w1f[(tap*3+chunk)*2+nt][lane][8] : oc=nt*16+(lane&15), cin=chunk*32+(lane>>4)*8+b
// conv2: w2f[tap*6+nt][lane][8]           : oc=nt*16+(lane&15), cin=(lane>>4)*8+b
__global__ void prep_frags(const float* __restrict__ w1, const float* __restrict__ w2,
                           ushort* __restrict__ w1f, ushort* __restrict__ w2f) {
    int t = blockIdx.x * 256 + threadIdx.x;
    if (t >= 10368) return;                 // 162 slots * 64 lanes
    int lane = t & 63, s = t >> 6;
    {   // conv1_w [32 oc][96 cin][27 tap]
        int nt = s & 1, sc = s >> 1;
        int chunk = sc % 3, tap = sc / 3;
        int oc = nt*16 + (lane & 15);
        int cb = chunk*32 + ((lane >> 4) << 3);
        ushort* dst = w1f + (size_t)t * 8;
        #pragma unroll
        for (int b = 0; b < 8; ++b) dst[b] = f2bf(w1[(oc*96 + cb + b)*27 + tap]);
    }
    {   // conv2_w [96 oc][32 cin][27 tap]
        int nt = s % 6, tap = s / 6;
        int oc = nt*16 + (lane & 15);
        int cb = (lane >> 4) << 3;
        ushort* dst = w2f + (size_t)t * 8;
        #pragma unroll
        for (int b = 0; b < 8; ++b) dst[b] = f2bf(w2[(oc*32 + cb + b)*27 + tap]);
    }
}

// ---------------- bias table: bias[h][n][m] = rpbt[rpi[n][m]][h] ----------------
__global__ void bias_gather(const int* __restrict__ rpi, const float* __restrict__ rpbt,
                            float* __restrict__ bias) {
    int t = blockIdx.x * 256 + threadIdx.x;
    if (t >= 512*512) return;
    int idx = rpi[t];
    #pragma unroll
    for (int h = 0; h < 6; ++h)
        bias[(size_t)h * 262144 + t] = rpbt[idx * 6 + h];
}

// ---------------- LayerNorm1: one wave per row ----------------
__global__ __launch_bounds__(256) void ln1_kernel(const float* __restrict__ x,
        const float* __restrict__ g, const float* __restrict__ b, float* __restrict__ out) {
    int row = blockIdx.x * 4 + (threadIdx.x >> 6);
    int lane = threadIdx.x & 63;
    const float* xr = x + (size_t)row * 96;
    float v0 = xr[lane];
    float v1 = (lane < 32) ? xr[64 + lane] : 0.0f;
    float s = v0 + v1, ss = v0*v0 + v1*v1;
    #pragma unroll
    for (int m = 32; m; m >>= 1) { s += __shfl_xor(s, m); ss += __shfl_xor(ss, m); }
    float mu = s * (1.0f/96.0f);
    float var = ss * (1.0f/96.0f) - mu*mu;
    float rs = rsqrtf(var + 1e-5f);
    float* orow = out + (size_t)row * 96;
    orow[lane] = (v0 - mu) * rs * g[lane] + b[lane];
    if (lane < 32) orow[64+lane] = (v1 - mu) * rs * g[64+lane] + b[64+lane];
}

// ---------------- generic tiled fp32 GEMM: C = act(A[M,K] @ B[N,K]^T + bias) (+res) ----------------
template<int ACT, int RES>
__global__ __launch_bounds__(256) void gemm_kernel(const float* __restrict__ A,
        const float* __restrict__ B, const float* __restrict__ bias,
        const float* __restrict__ res, float* __restrict__ Cout, int K, int N) {
    __shared__ float At[96][132];
    __shared__ float Bt[96][36];
    int m0 = blockIdx.x * 128;
    int n0 = blockIdx.y * 32;
    int tid = threadIdx.x;
    int tx = tid & 7, ty = tid >> 3;
    float acc[4][4] = {};
    for (int kc = 0; kc < K; kc += 96) {
        for (int i = tid; i < 128*24; i += 256) {
            int kq = i % 24, r = i / 24;
            float4 av = *(const float4*)(A + (size_t)(m0 + r)*K + kc + kq*4);
            At[kq*4+0][r] = av.x; At[kq*4+1][r] = av.y;
            At[kq*4+2][r] = av.z; At[kq*4+3][r] = av.w;
        }
        for (int i = tid; i < 32*24; i += 256) {
            int kq = i % 24, j = i / 24;
            float4 bv = *(const float4*)(B + (size_t)(n0 + j)*K + kc + kq*4);
            Bt[kq*4+0][j] = bv.x; Bt[kq*4+1][j] = bv.y;
            Bt[kq*4+2][j] = bv.z; Bt[kq*4+3][j] = bv.w;
        }
        __syncthreads();
        #pragma unroll 8
        for (int k = 0; k < 96; ++k) {
            float4 a4 = *(const float4*)&At[k][ty*4];
            float4 b4 = *(const float4*)&Bt[k][tx*4];
            float ar[4] = {a4.x, a4.y, a4.z, a4.w};
            float br[4] = {b4.x, b4.y, b4.z, b4.w};
            #pragma unroll
            for (int i = 0; i < 4; ++i)
                #pragma unroll
                for (int j = 0; j < 4; ++j)
                    acc[i][j] += ar[i] * br[j];
        }
        __syncthreads();
    }
    #pragma unroll
    for (int i = 0; i < 4; ++i) {
        int row = m0 + ty*4 + i;
        float o[4];
        #pragma unroll
        for (int j = 0; j < 4; ++j) {
            float v = acc[i][j] + bias[n0 + tx*4 + j];
            if (ACT == 1) v = gelu_exact(v);
            if (RES) v += res[(size_t)row * N + n0 + tx*4 + j];
            o[j] = v;
        }
        *(float4*)(Cout + (size_t)row * N + n0 + tx*4) = make_float4(o[0], o[1], o[2], o[3]);
    }
}

// ---------------- conv1 (96 -> 32) via bf16 MFMA implicit GEMM, + GELU, bf16 out ----
// block = one (d,h) row; 8 waves = Mtile(4) x Ntile(2); K = 27 taps x 96 cin
__global__ __launch_bounds__(512) void conv1_kernel(const float* __restrict__ xn,
        const ushort* __restrict__ w1f, const float* __restrict__ b1,
        ushort* __restrict__ c1out) {
    __shared__ ushort As[66 * 104];     // [vox+halo][96 cin bf16 + pad], 13.7 KB
    int blk = blockIdx.x;               // 512 = 8 d * 64 h
    int d = blk >> 6, hh = blk & 63;
    int tid = threadIdx.x;
    int lane = tid & 63, wave = tid >> 6;
    int mt = wave & 3, nt = wave >> 2;
    int arow = mt*16 + (lane & 15);
    int acol = (lane >> 4) << 3;
    f32x4 acc = {0.f, 0.f, 0.f, 0.f};
    for (int kd = -1; kd <= 1; ++kd) {
        int dd = d + kd;
        if ((unsigned)dd >= 8u) continue;
        for (int kh = -1; kh <= 1; ++kh) {
            int h2 = hh + kh;
            if ((unsigned)h2 >= 64u) continue;
            __syncthreads();
            const float* src = xn + (size_t)((dd*64 + h2)*64) * 96;
            for (int i = tid; i < 1536; i += 512) {      // 64 vox x 24 float4
                int v = i / 24, c4 = i % 24;
                float4 f = *(const float4*)(src + v*96 + c4*4);
                ushort4 o;
                o.x = f2bf(f.x); o.y = f2bf(f.y); o.z = f2bf(f.z); o.w = f2bf(f.w);
                *(ushort4*)&As[(v + 1)*104 + c4*4] = o;
            }
            if (tid < 48) {                              // halo rows -1, 64 -> zero
                int row = (tid < 24) ? 0 : 65;
                *(ushort4*)&As[row*104 + (tid % 24)*4] = make_ushort4(0,0,0,0);
            }
            __syncthreads();
            int tapbase = (kd+1)*9 + (kh+1)*3;
            #pragma unroll
            for (int kw = 0; kw < 3; ++kw) {
                #pragma unroll
                for (int chunk = 0; chunk < 3; ++chunk) {
                    bf16x8 a = *(const bf16x8*)&As[(arow + kw)*104 + chunk*32 + acol];
                    bf16x8 b = *(const bf16x8*)(w1f +
                        (size_t)((((tapbase + kw)*3 + chunk)*2 + nt)*64 + lane) * 8);
                    acc = __builtin_amdgcn_mfma_f32_16x16x32_bf16(a, b, acc, 0, 0, 0);
                }
            }
        }
    }
    int oc = nt*16 + (lane & 15);
    float bb = b1[oc];
    int vb = (d*64 + hh)*64 + mt*16 + ((lane >> 4) << 2);
    #pragma unroll
    for (int r = 0; r < 4; ++r) {
        float v = gelu_exact(acc[r] + bb);
        c1out[(size_t)(vb + r)*32 + oc] = f2bf(v);
    }
}

// ---------------- conv2 (32 -> 96) via bf16 MFMA implicit GEMM, fp32 out ----------
// block = one (d,h) row; 8 waves = Mtile(4) x NtilePair(2, 3 Ntiles each); K = 27x32
__global__ __launch_bounds__(512) void conv2_kernel(const ushort* __restrict__ c1,
        const ushort* __restrict__ w2f, const float* __restrict__ b2,
        float* __restrict__ y2) {
    __shared__ ushort As[66 * 40];      // [vox+halo][32 cin bf16 + pad], 5.3 KB
    int blk = blockIdx.x;
    int d = blk >> 6, hh = blk & 63;
    int tid = threadIdx.x;
    int lane = tid & 63, wave = tid >> 6;
    int mt = wave & 3, ntp = wave >> 2;
    int arow = mt*16 + (lane & 15);
    int acol = (lane >> 4) << 3;
    f32x4 acc[3] = {{0.f,0.f,0.f,0.f}, {0.f,0.f,0.f,0.f}, {0.f,0.f,0.f,0.f}};
    for (int kd = -1; kd <= 1; ++kd) {
        int dd = d + kd;
        if ((unsigned)dd >= 8u) continue;
        for (int kh = -1; kh <= 1; ++kh) {
            int h2 = hh + kh;
            if ((unsigned)h2 >= 64u) continue;
            __syncthreads();
            const ushort* src = c1 + (size_t)((dd*64 + h2)*64) * 32;
            {                                            // 64 vox x 8 ushort4 = 512 slots
                int v = tid >> 3, c = (tid & 7) * 4;
                *(ushort4*)&As[(v + 1)*40 + c] = *(const ushort4*)(src + v*32 + c);
            }
            if (tid < 20) {                              // halo rows: zero cols 0..39
                int row = (tid < 10) ? 0 : 65;
                *(ushort4*)&As[row*40 + (tid % 10)*4] = make_ushort4(0,0,0,0);
            }
            __syncthreads();
            int tapbase = (kd+1)*9 + (kh+1)*3;
            #pragma unroll
            for (int kw = 0; kw < 3; ++kw) {
                int tap = tapbase + kw;
                bf16x8 a = *(const bf16x8*)&As[(arow + kw)*40 + acol];
                #pragma unroll
                for (int j = 0; j < 3; ++j) {
                    bf16x8 b = *(const bf16x8*)(w2f +
                        (size_t)((tap*6 + ntp*3 + j)*64 + lane) * 8);
                    acc[j] = __builtin_amdgcn_mfma_f32_16x16x32_bf16(a, b, acc[j], 0, 0, 0);
                }
            }
        }
    }
    int vb = (d*64 + hh)*64 + mt*16 + ((lane >> 4) << 2);
    #pragma unroll
    for (int j = 0; j < 3; ++j) {
        int oc = (ntp*3 + j)*16 + (lane & 15);
        float bb = b2[oc];
        #pragma unroll
        for (int r = 0; r < 4; ++r)
            y2[(size_t)(vb + r)*96 + oc] = acc[j][r] + bb;
    }
}

// ---------------- global average pool (column sums, atomic) ----------------
__global__ void pool_kernel(const float* __restrict__ y2, float* __restrict__ p) {
    int c = threadIdx.x;               // block 128, 96 active
    if (c >= 96) return;
    int r0 = blockIdx.x * 64;
    float s = 0.0f;
    for (int r = 0; r < 64; ++r) s += y2[(size_t)(r0 + r)*96 + c];
    atomicAdd(&p[c], s);
}

// ---------------- channel attention: a = sigmoid(W2 relu(W1 mean + b1) + b2) ----------------
__global__ void ca_kernel(const float* __restrict__ p, const float* __restrict__ w1,
                          const float* __restrict__ b1, const float* __restrict__ w2,
                          const float* __restrict__ b2, float* __restrict__ a) {
    __shared__ float a1[3];
    int t = threadIdx.x;               // block 64
    if (t < 3) {
        float s = b1[t];
        for (int c = 0; c < 96; ++c) s += w1[t*96 + c] * (p[c] * (1.0f/32768.0f));
        a1[t] = fmaxf(s, 0.0f);
    }
    __syncthreads();
    for (int c = t; c < 96; c += 64) {
        float s = b2[c] + w2[c*3+0]*a1[0] + w2[c*3+1]*a1[1] + w2[c*3+2]*a1[2];
        a[c] = 1.0f / (1.0f + __expf(-s));
    }
}

// ---------------- windowed attention: one block per (window, head) ----------------
__global__ __launch_bounds__(256, 2) void attn_kernel(const float* __restrict__ qkv,
        const float* __restrict__ bias, float* __restrict__ oatt) {
    __shared__ float Ksh[512][16];
    __shared__ float Vsh[512][16];     // exactly 64 KiB
    int blk = blockIdx.x;
    int win = blk & 63;
    int h = blk >> 6;
    int hb = win >> 3, wb = win & 7;
    int tid = threadIdx.x;
    for (int n = tid; n < 512; n += 256) {
        int zd = n >> 6, zh = (n >> 3) & 7, zw = n & 7;
        int l = zd*4096 + (hb*8 + zh)*64 + wb*8 + zw;
        const float* kr = qkv + (size_t)l*288 + 96 + h*16;
        #pragma unroll
        for (int dq = 0; dq < 4; ++dq) {
            *(float4*)&Ksh[n][dq*4] = *(const float4*)(kr + dq*4);
            *(float4*)&Vsh[n][dq*4] = *(const float4*)(kr + 96 + dq*4);
        }
    }
    __syncthreads();
    int wave = tid >> 6, lane = tid & 63;
    int q0 = wave*64 + lane;
    int q1 = 256 + q0;
    int zd0 = q0 >> 6, zh0 = (q0 >> 3) & 7, zw0 = q0 & 7;
    int l0 = zd0*4096 + (hb*8 + zh0)*64 + wb*8 + zw0;
    int zd1 = q1 >> 6, zh1 = (q1 >> 3) & 7, zw1 = q1 & 7;
    int l1 = zd1*4096 + (hb*8 + zh1)*64 + wb*8 + zw1;
    float4 qa[4], qb[4];
    const float* q0p = qkv + (size_t)l0*288 + h*16;
    const float* q1p = qkv + (size_t)l1*288 + h*16;
    #pragma unroll
    for (int dq = 0; dq < 4; ++dq) {
        float4 t0 = *(const float4*)(q0p + dq*4);
        t0.x *= 0.25f; t0.y *= 0.25f; t0.z *= 0.25f; t0.w *= 0.25f;
        qa[dq] = t0;
        float4 t1 = *(const float4*)(q1p + dq*4);
        t1.x *= 0.25f; t1.y *= 0.25f; t1.z *= 0.25f; t1.w *= 0.25f;
        qb[dq] = t1;
    }
    const float* brow0 = bias + (size_t)h*262144 + (size_t)q0*512;
    const float* brow1 = bias + (size_t)h*262144 + (size_t)q1*512;
    float m0 = -1e30f, m1 = -1e30f, sum0 = 0.0f, sum1 = 0.0f;
    float4 o0[4], o1[4];
    #pragma unroll
    for (int dq = 0; dq < 4; ++dq) { o0[dq] = make_float4(0,0,0,0); o1[dq] = make_float4(0,0,0,0); }
    for (int kt = 0; kt < 16; ++kt) {
        int kb = kt * 32;
        float s0[32], s1[32];
        #pragma unroll
        for (int jq = 0; jq < 8; ++jq) {
            float4 b0 = *(const float4*)(brow0 + kb + jq*4);
            s0[jq*4+0] = b0.x; s0[jq*4+1] = b0.y; s0[jq*4+2] = b0.z; s0[jq*4+3] = b0.w;
            float4 b1v = *(const float4*)(brow1 + kb + jq*4);
            s1[jq*4+0] = b1v.x; s1[jq*4+1] = b1v.y; s1[jq*4+2] = b1v.z; s1[jq*4+3] = b1v.w;
        }
        #pragma unroll
        for (int j = 0; j < 32; ++j) {
            float a0 = s0[j], a1v = s1[j];
            #pragma unroll
            for (int dq = 0; dq < 4; ++dq) {
                float4 kv = *(const float4*)&Ksh[kb + j][dq*4];
                a0  += dot4(qa[dq], kv);
                a1v += dot4(qb[dq], kv);
            }
            s0[j] = a0; s1[j] = a1v;
        }
        float tm0 = s0[0], tm1 = s1[0];
        #pragma unroll
        for (int j = 1; j < 32; ++j) { tm0 = fmaxf(tm0, s0[j]); tm1 = fmaxf(tm1, s1[j]); }
        float nm0 = fmaxf(m0, tm0), nm1 = fmaxf(m1, tm1);
        float c0 = __expf(m0 - nm0), c1v = __expf(m1 - nm1);
        m0 = nm0; m1 = nm1;
        sum0 *= c0; sum1 *= c1v;
        #pragma unroll
        for (int dq = 0; dq < 4; ++dq) {
            o0[dq].x *= c0;  o0[dq].y *= c0;  o0[dq].z *= c0;  o0[dq].w *= c0;
            o1[dq].x *= c1v; o1[dq].y *= c1v; o1[dq].z *= c1v; o1[dq].w *= c1v;
        }
        #pragma unroll
        for (int j = 0; j < 32; ++j) {
            float p0 = __expf(s0[j] - nm0);
            float p1 = __expf(s1[j] - nm1);
            sum0 += p0; sum1 += p1;
            s0[j] = p0; s1[j] = p1;
        }
        #pragma unroll
        for (int j = 0; j < 32; ++j) {
            float p0 = s0[j], p1 = s1[j];
            #pragma unroll
            for (int dq = 0; dq < 4; ++dq) {
                float4 vv = *(const float4*)&Vsh[kb + j][dq*4];
                o0[dq].x += p0*vv.x; o0[dq].y += p0*vv.y; o0[dq].z += p0*vv.z; o0[dq].w += p0*vv.w;
                o1[dq].x += p1*vv.x; o1[dq].y += p1*vv.y; o1[dq].z += p1*vv.z; o1[dq].w += p1*vv.w;
            }
        }
    }
    float inv0 = 1.0f / sum0, inv1 = 1.0f / sum1;
    float* op0 = oatt + (size_t)l0*96 + h*16;
    float* op1 = oatt + (size_t)l1*96 + h*16;
    #pragma unroll
    for (int dq = 0; dq < 4; ++dq) {
        *(float4*)(op0 + dq*4) = make_float4(o0[dq].x*inv0, o0[dq].y*inv0, o0[dq].z*inv0, o0[dq].w*inv0);
        *(float4*)(op1 + dq*4) = make_float4(o1[dq].x*inv1, o1[dq].y*inv1, o1[dq].z*inv1, o1[dq].w*inv1);
    }
}

// ---------------- residual (x + proj + 0.01*y2*a) + LayerNorm2, fused ----------------
__global__ __launch_bounds__(256) void resid_ln2_kernel(const float* __restrict__ x,
        const float* __restrict__ po, const float* __restrict__ y2, const float* __restrict__ a,
        const float* __restrict__ g, const float* __restrict__ b,
        float* __restrict__ x2, float* __restrict__ xn2) {
    int row = blockIdx.x * 4 + (threadIdx.x >> 6);
    int lane = threadIdx.x & 63;
    size_t base = (size_t)row * 96;
    float v0 = x[base + lane] + po[base + lane] + 0.01f * y2[base + lane] * a[lane];
    float v1 = 0.0f;
    if (lane < 32) {
        int c = 64 + lane;
        v1 = x[base + c] + po[base + c] + 0.01f * y2[base + c] * a[c];
    }
    x2[base + lane] = v0;
    if (lane < 32) x2[base + 64 + lane] = v1;
    float s = v0 + v1, ss = v0*v0 + v1*v1;
    #pragma unroll
    for (int m = 32; m; m >>= 1) { s += __shfl_xor(s, m); ss += __shfl_xor(ss, m); }
    float mu = s * (1.0f/96.0f);
    float var = ss * (1.0f/96.0f) - mu*mu;
    float rs = rsqrtf(var + 1e-5f);
    xn2[base + lane] = (v0 - mu) * rs * g[lane] + b[lane];
    if (lane < 32) xn2[base + 64 + lane] = (v1 - mu) * rs * g[64+lane] + b[64+lane];
}

extern "C" void kernel_launch(void* const* d_in, const int* in_sizes, int n_in,
                              void* d_out, int out_size, void* d_ws, size_t ws_size,
                              hipStream_t stream) {
    const float* x      = (const float*)d_in[0];
    const float* n1g    = (const float*)d_in[1];
    const float* n1b    = (const float*)d_in[2];
    const float* qkv_w  = (const float*)d_in[3];
    const float* qkv_b  = (const float*)d_in[4];
    const float* rpbt   = (const float*)d_in[5];
    const float* proj_w = (const float*)d_in[6];
    const float* proj_b = (const float*)d_in[7];
    const float* c1w    = (const float*)d_in[8];
    const float* c1b    = (const float*)d_in[9];
    const float* c2w    = (const float*)d_in[10];
    const float* c2b    = (const float*)d_in[11];
    const float* ca1w   = (const float*)d_in[12];
    const float* ca1b   = (const float*)d_in[13];
    const float* ca2w   = (const float*)d_in[14];
    const float* ca2b   = (const float*)d_in[15];
    const float* n2g    = (const float*)d_in[16];
    const float* n2b    = (const float*)d_in[17];
    const float* fc1w   = (const float*)d_in[18];
    const float* fc1b   = (const float*)d_in[19];
    const float* fc2w   = (const float*)d_in[20];
    const float* fc2b   = (const float*)d_in[21];
    const int*   rpi    = (const int*)d_in[22];

    // ---- workspace layout with lifetime-based aliasing (floats) ----
    float* W    = (float*)d_ws;
    float* xn   = W;                     // 3,145,728
    float* oat  = W;                     // aliases xn
    float* qkvb = W + 3145728;           // 9,437,184
    float* po   = W + 3145728;           // aliases qkvb[0:3.14M)
    float* x2   = W + 6291456;           // aliases qkvb[3.14M:6.29M)
    float* xn2  = W + 9437184;           // aliases qkvb[6.29M:9.44M)
    float* bias = W + 12582912;          // 1,572,864
    ushort* c1u = (ushort*)(W + 14155776);   // 2 MB bf16 (region 4 MB)
    float* y2   = W + 15204352;          // 3,145,728
    float* hbuf = W + 12582912;          // 12,582,912 (aliases bias+c1+y2, dead by fc1)
    ushort* w1f = (ushort*)(W + 25165824);   // 165,888 B (region 331 KB)
    ushort* w2f = (ushort*)(W + 25248768);   // 165,888 B
    float* pbuf = W + 25331712;          // 96
    float* abuf = W + 25331808;          // 96

    prep_frags<<<41, 256, 0, stream>>>(c1w, c2w, w1f, w2f);
    bias_gather<<<1024, 256, 0, stream>>>(rpi, rpbt, bias);
    ln1_kernel<<<8192, 256, 0, stream>>>(x, n1g, n1b, xn);
    gemm_kernel<0,0><<<dim3(256, 9), 256, 0, stream>>>(xn, qkv_w, qkv_b, nullptr, qkvb, 96, 288);
    conv1_kernel<<<512, 512, 0, stream>>>(xn, w1f, c1b, c1u);
    conv2_kernel<<<512, 512, 0, stream>>>(c1u, w2f, c2b, y2);
    hipMemsetAsync(pbuf, 0, 96*sizeof(float), stream);
    pool_kernel<<<512, 128, 0, stream>>>(y2, pbuf);
    ca_kernel<<<1, 64, 0, stream>>>(pbuf, ca1w, ca1b, ca2w, ca2b, abuf);
    attn_kernel<<<384, 256, 0, stream>>>(qkvb, bias, oat);
    gemm_kernel<0,0><<<dim3(256, 3), 256, 0, stream>>>(oat, proj_w, proj_b, nullptr, po, 96, 96);
    resid_ln2_kernel<<<8192, 256, 0, stream>>>(x, po, y2, abuf, n2g, n2b, x2, xn2);
    gemm_kernel<1,0><<<dim3(256, 12), 256, 0, stream>>>(xn2, fc1w, fc1b, nullptr, hbuf, 96, 384);
    gemm_kernel<0,1><<<dim3(256, 3), 256, 0, stream>>>(hbuf, fc2w, fc2b, x2, (float*)d_out, 384, 96);
}